// Round 13
// baseline (174.114 us; speedup 1.0000x reference)
//
#include <hip/hip_runtime.h>
#include <cstddef>

constexpr int Bn = 16, Dn = 512, Nn = 4096, Kn = 64;
constexpr int PN = 128;            // panel n-size
constexpr int Dp = 520;            // padded aggp pitch (non-pow2)
constexpr float FEPS = 1e-12f;

typedef __bf16 bf16x8 __attribute__((ext_vector_type(8)));
typedef float f32x4 __attribute__((ext_vector_type(4)));

__device__ __forceinline__ unsigned short bf_bits(__bf16 h) {
  union { __bf16 b; unsigned short u; } c;
  c.b = h;
  return c.u;
}

// ---------------------------------------------------------------------------
// kW: split conv_w[K][D] (row-major, d-contiguous) into bf16 hi/lo arrays.
// ---------------------------------------------------------------------------
__global__ __launch_bounds__(256) void kW(const float* __restrict__ w,
                                          unsigned short* __restrict__ w_hi,
                                          unsigned short* __restrict__ w_lo) {
  const int idx = blockIdx.x * 256 + threadIdx.x;  // 32768 total
  const float v = w[idx];
  const __bf16 h = (__bf16)v;          // RNE
  const float r = v - (float)h;
  const __bf16 l = (__bf16)r;
  w_hi[idx] = bf_bits(h);
  w_lo[idx] = bf_bits(l);
}

// ---------------------------------------------------------------------------
// kF v5: R12's kernel with ONE change: phase-1 staging is a 4-DEEP
// statically-rotated prefetch pipeline (64 KB in flight per block vs 16 KB).
// At each chunk store the compiler now waits vmcnt(6) (3 newer chunks stay
// in flight) instead of draining — each load gets ~4 chunk-cycles to land.
// All math bit-identical to R12 (validated, absmax 6.1e-5).
// Block = (b, superpanel sp of 256 n), 512 thr = 8 waves, grid 256 = 1/CU.
// ---------------------------------------------------------------------------
__global__ __launch_bounds__(512, 2) void kF(const float* __restrict__ x,
                                             const unsigned short* __restrict__ w_hi,
                                             const unsigned short* __restrict__ w_lo,
                                             const float* __restrict__ conv_b,
                                             float* __restrict__ aggp,
                                             float* __restrict__ massp) {
  __shared__ float xs[PN * 33];             // staging / as_hi reuse
  __shared__ unsigned short xhi[Dn * PN];   // persistent bf16-hi panel
  __shared__ float msum[8][64];
  const int tid = threadIdx.x;
  const int l = tid & 63;
  const int wv = tid >> 6;   // 0..7
  const int ll = l & 15;
  const int lg = l >> 4;
  const int b = blockIdx.x >> 4;
  const int sp = blockIdx.x & 15;
  const int srow = tid >> 4;        // 0..31 (staging row within 32-d chunk)
  const int sc0 = (tid & 15) << 3;  // staging col (8 n per thread)
  const int ncol = (wv << 4) + ll;  // phase-1 n within panel

  f32x4 acc2[4][4];
#pragma unroll
  for (int kt = 0; kt < 4; ++kt)
#pragma unroll
    for (int dt = 0; dt < 4; ++dt) acc2[kt][dt] = (f32x4){0.f, 0.f, 0.f, 0.f};

  for (int rep = 0; rep < 2; ++rep) {
    const int p = (sp << 1) + rep;
    const int n0 = p << 7;
    const float* xbp = x + (size_t)b * Dn * Nn + n0;

    // =================== Phase 1: logits (validated math) ===================
    f32x4 acc[4];
#pragma unroll
    for (int kt = 0; kt < 4; ++kt) acc[kt] = (f32x4){0.f, 0.f, 0.f, 0.f};
    float ss = 0.f;

    // 4-deep prefetch pipeline: issue chunks 0..3
    float4 pf[4][2];
#pragma unroll
    for (int s = 0; s < 4; ++s) {
      const float* src = xbp + (size_t)(s * 32 + srow) * Nn + sc0;
      pf[s][0] = *(const float4*)(src);
      pf[s][1] = *(const float4*)(src + 4);
    }

#pragma unroll
    for (int it = 0; it < 16; ++it) {
      const int s = it & 3;          // static (fully unrolled)
      const int dc = it * 32;
      // ---- store stage s (fp32 transposed + bf16-hi panel) ----
      {
        const float pv[8] = {pf[s][0].x, pf[s][0].y, pf[s][0].z, pf[s][0].w,
                             pf[s][1].x, pf[s][1].y, pf[s][1].z, pf[s][1].w};
#pragma unroll
        for (int j = 0; j < 8; ++j) xs[(sc0 + j) * 33 + srow] = pv[j];
        unsigned short hb[8];
#pragma unroll
        for (int j = 0; j < 8; ++j) hb[j] = bf_bits((__bf16)pv[j]);
        const unsigned byteoff =
            (unsigned)(((dc + srow) * PN + sc0) * 2) ^ ((unsigned)(srow & 7) << 4);
        uint4 hv;
        hv.x = (unsigned)hb[0] | ((unsigned)hb[1] << 16);
        hv.y = (unsigned)hb[2] | ((unsigned)hb[3] << 16);
        hv.z = (unsigned)hb[4] | ((unsigned)hb[5] << 16);
        hv.w = (unsigned)hb[6] | ((unsigned)hb[7] << 16);
        *(uint4*)((char*)xhi + byteoff) = hv;
      }
      // ---- refill stage s with chunk it+4 ----
      if (it < 12) {
        const float* src = xbp + (size_t)(dc + 128 + srow) * Nn + sc0;
        pf[s][0] = *(const float4*)(src);
        pf[s][1] = *(const float4*)(src + 4);
      }
      asm volatile("s_waitcnt lgkmcnt(0)\ns_barrier" ::: "memory");

      // ---- consume chunk dc ----
      float xv[8];
#pragma unroll
      for (int j = 0; j < 8; ++j) xv[j] = xs[ncol * 33 + lg * 8 + j];
      bf16x8 bh, bl;
#pragma unroll
      for (int j = 0; j < 8; ++j) {
        ss = fmaf(xv[j], xv[j], ss);
        const __bf16 h = (__bf16)xv[j];
        bh[j] = h;
        bl[j] = (__bf16)(xv[j] - (float)h);
      }
#pragma unroll
      for (int kt = 0; kt < 4; ++kt) {
        const size_t woff = (size_t)(kt * 16 + ll) * Dn + dc + lg * 8;
        bf16x8 ah = *(const bf16x8*)(w_hi + woff);
        bf16x8 al = *(const bf16x8*)(w_lo + woff);
        acc[kt] = __builtin_amdgcn_mfma_f32_16x16x32_bf16(ah, bh, acc[kt], 0, 0, 0);
        acc[kt] = __builtin_amdgcn_mfma_f32_16x16x32_bf16(ah, bl, acc[kt], 0, 0, 0);
        acc[kt] = __builtin_amdgcn_mfma_f32_16x16x32_bf16(al, bh, acc[kt], 0, 0, 0);
      }
      asm volatile("s_waitcnt lgkmcnt(0)\ns_barrier" ::: "memory");
    }

    // ---- softmax (in-register, validated) ----
    ss += __shfl_xor(ss, 16);
    ss += __shfl_xor(ss, 32);
    const float iv = 1.f / fmaxf(sqrtf(ss), FEPS);
    float lgt[16];
#pragma unroll
    for (int kt = 0; kt < 4; ++kt)
#pragma unroll
      for (int r = 0; r < 4; ++r)
        lgt[kt * 4 + r] = fmaf(acc[kt][r], iv, conv_b[kt * 16 + lg * 4 + r]);
    float pmax = lgt[0];
#pragma unroll
    for (int i = 1; i < 16; ++i) pmax = fmaxf(pmax, lgt[i]);
    pmax = fmaxf(pmax, __shfl_xor(pmax, 16));
    pmax = fmaxf(pmax, __shfl_xor(pmax, 32));
    float ex[16];
    float psum = 0.f;
#pragma unroll
    for (int i = 0; i < 16; ++i) {
      ex[i] = expf(lgt[i] - pmax);
      psum += ex[i];
    }
    psum += __shfl_xor(psum, 16);
    psum += __shfl_xor(psum, 32);
    const float isum = 1.f / psum;

    __syncthreads();  // xs reads done; reuse as as_hi

    unsigned short* as_hi = (unsigned short*)xs;  // [ng16][k64][8] bf16
    const int ngb = (wv << 1) + (ll >> 3);
    const int jj = ll & 7;
#pragma unroll
    for (int i = 0; i < 16; ++i) {
      const int k = (i >> 2) * 16 + lg * 4 + (i & 3);
      const float a = ex[i] * isum;
      as_hi[(ngb * 64 + k) * 8 + jj] = bf_bits((__bf16)(a * iv));
      float m = a;
      m += __shfl_xor(m, 1);
      m += __shfl_xor(m, 2);
      m += __shfl_xor(m, 4);
      m += __shfl_xor(m, 8);
      if (ll == 0) msum[wv][k] = m;
    }
    __syncthreads();
    if (tid < 64) {
      float s = 0.f;
#pragma unroll
      for (int ww = 0; ww < 8; ++ww) s += msum[ww][tid];
      massp[((b << 5) + p) * Kn + tid] = s;
    }

    // =================== Phase 2: agg from LDS ===================
    // wave wv -> d in [wv*64, wv*64+64); A = as_hi (LDS), B = xhi (LDS)
#pragma unroll
    for (int nc = 0; nc < PN; nc += 32) {
      const int ng = (nc >> 3) + lg;
      bf16x8 af[4];
#pragma unroll
      for (int kt = 0; kt < 4; ++kt)
        af[kt] = *(const bf16x8*)(as_hi + (ng * 64 + kt * 16 + ll) * 8);
#pragma unroll
      for (int dt = 0; dt < 4; ++dt) {
        const int d = wv * 64 + dt * 16 + ll;
        const unsigned byteoff =
            (unsigned)((d * PN + nc + lg * 8) * 2) ^ ((unsigned)(d & 7) << 4);
        bf16x8 bx = *(const bf16x8*)((const char*)xhi + byteoff);
#pragma unroll
        for (int kt = 0; kt < 4; ++kt)
          acc2[kt][dt] = __builtin_amdgcn_mfma_f32_16x16x32_bf16(
              af[kt], bx, acc2[kt][dt], 0, 0, 0);
      }
    }
    __syncthreads();  // phase-2 LDS reads done before next rep overwrites
  }

  // store partials: aggp[((b*16+sp)*64 + k)*Dp + d]
  float* outb = aggp + (size_t)((b << 4) + sp) * Kn * Dp;
#pragma unroll
  for (int kt = 0; kt < 4; ++kt)
#pragma unroll
    for (int dt = 0; dt < 4; ++dt) {
      const int krow = kt * 16 + (lg << 2);
      const int dcol = wv * 64 + dt * 16 + ll;
      float* op = outb + (size_t)krow * Dp + dcol;
#pragma unroll
      for (int r = 0; r < 4; ++r) op[(size_t)r * Dp] = acc2[kt][dt][r];
    }
}

// ---------------------------------------------------------------------------
// kC1: per (b,k): mass from massp (32 panels); vlad = sum(aggp over 16
// superpanels) - mass*c; intra-normalize over d.
// ---------------------------------------------------------------------------
__device__ __forceinline__ float blockReduceSum(float v, float* sb) {
#pragma unroll
  for (int off = 32; off > 0; off >>= 1) v += __shfl_down(v, off, 64);
  const int lane = threadIdx.x & 63, w = threadIdx.x >> 6;
  if (lane == 0) sb[w] = v;
  __syncthreads();
  if (threadIdx.x == 0) sb[4] = sb[0] + sb[1] + sb[2] + sb[3];
  __syncthreads();
  return sb[4];
}

__global__ __launch_bounds__(256) void kC1(const float* __restrict__ massp,
                                           const float* __restrict__ aggp,
                                           const float* __restrict__ centroids,
                                           float* __restrict__ out,
                                           float* __restrict__ rowsq) {
  __shared__ float sb[5];
  const int tid = threadIdx.x;
  const int b = blockIdx.x >> 6, k = blockIdx.x & 63;
  float s = 0.f;
  if (tid < 32) s = massp[((b << 5) + tid) * Kn + k];
  const float mass = blockReduceSum(s, sb);
  float v[2];
  float sq = 0.f;
#pragma unroll
  for (int u = 0; u < 2; ++u) {
    const int d = tid + (u << 8);
    float val = -mass * centroids[k * Dn + d];
#pragma unroll
    for (int pp = 0; pp < 16; ++pp)
      val += aggp[((size_t)((b << 4) + pp) * Kn + k) * Dp + d];
    v[u] = val;
    sq = fmaf(val, val, sq);
  }
  const float rsq = blockReduceSum(sq, sb);
  const float inv = 1.f / fmaxf(sqrtf(rsq), FEPS);
#pragma unroll
  for (int u = 0; u < 2; ++u)
    out[((size_t)b * Kn + k) * Dn + tid + (u << 8)] = v[u] * inv;
  if (tid == 0) rowsq[b * Kn + k] = rsq * inv * inv;
}

// ---------------------------------------------------------------------------
// kC2: final global L2 norm per batch.
// ---------------------------------------------------------------------------
__global__ __launch_bounds__(256) void kC2(float* __restrict__ out,
                                           const float* __restrict__ rowsq) {
  __shared__ float sg;
  const int b = blockIdx.x, tid = threadIdx.x;
  float v = (tid < 64) ? rowsq[b * Kn + tid] : 0.f;
  if (tid < 64) {
#pragma unroll
    for (int off = 32; off > 0; off >>= 1) v += __shfl_down(v, off, 64);
  }
  if (tid == 0) sg = 1.f / fmaxf(sqrtf(v), FEPS);
  __syncthreads();
  const float inv = sg;
  float* ob = out + (size_t)b * (Kn * Dn);
  for (int t = tid; t < Kn * Dn; t += 256) ob[t] *= inv;
}

// ---------------------------------------------------------------------------
extern "C" void kernel_launch(void* const* d_in, const int* in_sizes, int n_in,
                              void* d_out, int out_size, void* d_ws,
                              size_t ws_size, hipStream_t stream) {
  const float* x = (const float*)d_in[0];
  const float* centroids = (const float*)d_in[1];
  const float* conv_w = (const float*)d_in[2];
  const float* conv_b = (const float*)d_in[3];
  float* out = (float*)d_out;
  float* ws = (float*)d_ws;
  // ws layout (float units):
  //   aggp    [0,        8519680)  16 b x 16 sp x 64 k x Dp(520) f32
  //   w_hi    [8519680,  8536064)  64x512 bf16 = 16384 floats
  //   w_lo    [8536064,  8552448)
  //   massp   [8552448,  8585216)  16 b x 32 p x 64 k
  //   rowsq   [8585216,  8586240)
  float* aggp = ws;
  unsigned short* w_hi = (unsigned short*)(ws + 8519680);
  unsigned short* w_lo = (unsigned short*)(ws + 8536064);
  float* massp = ws + 8552448;
  float* rowsq = ws + 8585216;

  kW<<<128, 256, 0, stream>>>(conv_w, w_hi, w_lo);
  kF<<<256, 512, 0, stream>>>(x, w_hi, w_lo, conv_b, aggp, massp);
  kC1<<<1024, 256, 0, stream>>>(massp, aggp, centroids, out, rowsq);
  kC2<<<16, 256, 0, stream>>>(out, rowsq);
}

// Round 14
// 161.662 us; speedup vs baseline: 1.0770x; 1.0770x over previous
//
#include <hip/hip_runtime.h>
#include <cstddef>

constexpr int Bn = 16, Dn = 512, Nn = 4096, Kn = 64;
constexpr int PN = 128;            // panel n-size
constexpr int Dp = 520;            // padded aggp pitch (non-pow2)
constexpr int Npitch = 4224;       // padded xp row pitch (16896 B, non-pow2)
constexpr float FEPS = 1e-12f;

typedef __bf16 bf16x8 __attribute__((ext_vector_type(8)));
typedef float f32x4 __attribute__((ext_vector_type(4)));

__device__ __forceinline__ unsigned short bf_bits(__bf16 h) {
  union { __bf16 b; unsigned short u; } c;
  c.b = h;
  return c.u;
}

// ---------------------------------------------------------------------------
// kX: padded copy x[b][d][4096] -> xp[b][d][Npitch]. Fully-sequential read,
// near-sequential write; breaks the 16KB pow2 row stride so kF's strided
// row reads spread across DRAM banks/channels.
// ---------------------------------------------------------------------------
__global__ __launch_bounds__(256) void kX(const float* __restrict__ x,
                                          float* __restrict__ xp) {
  const size_t stride = (size_t)gridDim.x * 256;
  const size_t total = (size_t)Bn * Dn * Nn / 4;  // uint4 count
  for (size_t i = (size_t)blockIdx.x * 256 + threadIdx.x; i < total; i += stride) {
    const size_t idx = i << 2;          // float index
    const size_t bd = idx >> 12;        // b*Dn + d  (Nn = 4096)
    const int n = (int)(idx & 4095);
    *(uint4*)(xp + bd * Npitch + n) = *(const uint4*)(x + idx);
  }
}

// ---------------------------------------------------------------------------
// kW: split conv_w[K][D] (row-major, d-contiguous) into bf16 hi/lo arrays.
// ---------------------------------------------------------------------------
__global__ __launch_bounds__(256) void kW(const float* __restrict__ w,
                                          unsigned short* __restrict__ w_hi,
                                          unsigned short* __restrict__ w_lo) {
  const int idx = blockIdx.x * 256 + threadIdx.x;  // 32768 total
  const float v = w[idx];
  const __bf16 h = (__bf16)v;          // RNE
  const float r = v - (float)h;
  const __bf16 l = (__bf16)r;
  w_hi[idx] = bf_bits(h);
  w_lo[idx] = bf_bits(l);
}

// ---------------------------------------------------------------------------
// kF v6 = R12's validated kernel (depth-1 staging, math bit-identical),
// reading the PADDED xp instead of x in phase 1. Phase 2 reads LDS (as
// before). Block = (b, superpanel sp of 256 n), 512 thr = 8 waves.
// ---------------------------------------------------------------------------
__global__ __launch_bounds__(512, 2) void kF(const float* __restrict__ xp,
                                             const unsigned short* __restrict__ w_hi,
                                             const unsigned short* __restrict__ w_lo,
                                             const float* __restrict__ conv_b,
                                             float* __restrict__ aggp,
                                             float* __restrict__ massp) {
  __shared__ float xs[PN * 33];             // staging / as_hi reuse
  __shared__ unsigned short xhi[Dn * PN];   // persistent bf16-hi panel
  __shared__ float msum[8][64];
  const int tid = threadIdx.x;
  const int l = tid & 63;
  const int wv = tid >> 6;   // 0..7
  const int ll = l & 15;
  const int lg = l >> 4;
  const int b = blockIdx.x >> 4;
  const int sp = blockIdx.x & 15;
  const int srow = tid >> 4;        // 0..31 (staging row within 32-d chunk)
  const int sc0 = (tid & 15) << 3;  // staging col (8 n per thread)
  const int ncol = (wv << 4) + ll;  // phase-1 n within panel

  f32x4 acc2[4][4];
#pragma unroll
  for (int kt = 0; kt < 4; ++kt)
#pragma unroll
    for (int dt = 0; dt < 4; ++dt) acc2[kt][dt] = (f32x4){0.f, 0.f, 0.f, 0.f};

  for (int rep = 0; rep < 2; ++rep) {
    const int p = (sp << 1) + rep;
    const int n0 = p << 7;
    const float* xbp = xp + (size_t)b * Dn * Npitch + n0;

    // =================== Phase 1: logits (validated math) ===================
    f32x4 acc[4];
#pragma unroll
    for (int kt = 0; kt < 4; ++kt) acc[kt] = (f32x4){0.f, 0.f, 0.f, 0.f};
    float ss = 0.f;

    float4 pf0 = *(const float4*)(xbp + (size_t)srow * Npitch + sc0);
    float4 pf1 = *(const float4*)(xbp + (size_t)srow * Npitch + sc0 + 4);

    for (int dc = 0; dc < Dn; dc += 32) {
      // stage fp32 transposed [n][33] + bf16-hi into persistent panel
      const float pv[8] = {pf0.x, pf0.y, pf0.z, pf0.w, pf1.x, pf1.y, pf1.z, pf1.w};
#pragma unroll
      for (int j = 0; j < 8; ++j) xs[(sc0 + j) * 33 + srow] = pv[j];
      {
        unsigned short hb[8];
#pragma unroll
        for (int j = 0; j < 8; ++j) hb[j] = bf_bits((__bf16)pv[j]);
        const unsigned byteoff =
            (unsigned)(((dc + srow) * PN + sc0) * 2) ^ ((unsigned)(srow & 7) << 4);
        uint4 hv;
        hv.x = (unsigned)hb[0] | ((unsigned)hb[1] << 16);
        hv.y = (unsigned)hb[2] | ((unsigned)hb[3] << 16);
        hv.z = (unsigned)hb[4] | ((unsigned)hb[5] << 16);
        hv.w = (unsigned)hb[6] | ((unsigned)hb[7] << 16);
        *(uint4*)((char*)xhi + byteoff) = hv;
      }
      if (dc + 32 < Dn) {
        pf0 = *(const float4*)(xbp + (size_t)(dc + 32 + srow) * Npitch + sc0);
        pf1 = *(const float4*)(xbp + (size_t)(dc + 32 + srow) * Npitch + sc0 + 4);
      }
      asm volatile("s_waitcnt lgkmcnt(0)\ns_barrier" ::: "memory");

      // consume chunk
      float xv[8];
#pragma unroll
      for (int j = 0; j < 8; ++j) xv[j] = xs[ncol * 33 + lg * 8 + j];
      bf16x8 bh, bl;
#pragma unroll
      for (int j = 0; j < 8; ++j) {
        ss = fmaf(xv[j], xv[j], ss);
        const __bf16 h = (__bf16)xv[j];
        bh[j] = h;
        bl[j] = (__bf16)(xv[j] - (float)h);
      }
#pragma unroll
      for (int kt = 0; kt < 4; ++kt) {
        const size_t woff = (size_t)(kt * 16 + ll) * Dn + dc + lg * 8;
        bf16x8 ah = *(const bf16x8*)(w_hi + woff);
        bf16x8 al = *(const bf16x8*)(w_lo + woff);
        acc[kt] = __builtin_amdgcn_mfma_f32_16x16x32_bf16(ah, bh, acc[kt], 0, 0, 0);
        acc[kt] = __builtin_amdgcn_mfma_f32_16x16x32_bf16(ah, bl, acc[kt], 0, 0, 0);
        acc[kt] = __builtin_amdgcn_mfma_f32_16x16x32_bf16(al, bh, acc[kt], 0, 0, 0);
      }
      asm volatile("s_waitcnt lgkmcnt(0)\ns_barrier" ::: "memory");
    }

    // ---- softmax (in-register, validated) ----
    ss += __shfl_xor(ss, 16);
    ss += __shfl_xor(ss, 32);
    const float iv = 1.f / fmaxf(sqrtf(ss), FEPS);
    float lgt[16];
#pragma unroll
    for (int kt = 0; kt < 4; ++kt)
#pragma unroll
      for (int r = 0; r < 4; ++r)
        lgt[kt * 4 + r] = fmaf(acc[kt][r], iv, conv_b[kt * 16 + lg * 4 + r]);
    float pmax = lgt[0];
#pragma unroll
    for (int i = 1; i < 16; ++i) pmax = fmaxf(pmax, lgt[i]);
    pmax = fmaxf(pmax, __shfl_xor(pmax, 16));
    pmax = fmaxf(pmax, __shfl_xor(pmax, 32));
    float ex[16];
    float psum = 0.f;
#pragma unroll
    for (int i = 0; i < 16; ++i) {
      ex[i] = expf(lgt[i] - pmax);
      psum += ex[i];
    }
    psum += __shfl_xor(psum, 16);
    psum += __shfl_xor(psum, 32);
    const float isum = 1.f / psum;

    __syncthreads();  // xs reads done; reuse as as_hi

    unsigned short* as_hi = (unsigned short*)xs;  // [ng16][k64][8] bf16
    const int ngb = (wv << 1) + (ll >> 3);
    const int jj = ll & 7;
#pragma unroll
    for (int i = 0; i < 16; ++i) {
      const int k = (i >> 2) * 16 + lg * 4 + (i & 3);
      const float a = ex[i] * isum;
      as_hi[(ngb * 64 + k) * 8 + jj] = bf_bits((__bf16)(a * iv));
      float m = a;
      m += __shfl_xor(m, 1);
      m += __shfl_xor(m, 2);
      m += __shfl_xor(m, 4);
      m += __shfl_xor(m, 8);
      if (ll == 0) msum[wv][k] = m;
    }
    __syncthreads();
    if (tid < 64) {
      float s = 0.f;
#pragma unroll
      for (int ww = 0; ww < 8; ++ww) s += msum[ww][tid];
      massp[((b << 5) + p) * Kn + tid] = s;
    }

    // =================== Phase 2: agg from LDS ===================
    // wave wv -> d in [wv*64, wv*64+64); A = as_hi (LDS), B = xhi (LDS)
#pragma unroll
    for (int nc = 0; nc < PN; nc += 32) {
      const int ng = (nc >> 3) + lg;
      bf16x8 af[4];
#pragma unroll
      for (int kt = 0; kt < 4; ++kt)
        af[kt] = *(const bf16x8*)(as_hi + (ng * 64 + kt * 16 + ll) * 8);
#pragma unroll
      for (int dt = 0; dt < 4; ++dt) {
        const int d = wv * 64 + dt * 16 + ll;
        const unsigned byteoff =
            (unsigned)((d * PN + nc + lg * 8) * 2) ^ ((unsigned)(d & 7) << 4);
        bf16x8 bx = *(const bf16x8*)((const char*)xhi + byteoff);
#pragma unroll
        for (int kt = 0; kt < 4; ++kt)
          acc2[kt][dt] = __builtin_amdgcn_mfma_f32_16x16x32_bf16(
              af[kt], bx, acc2[kt][dt], 0, 0, 0);
      }
    }
    __syncthreads();  // phase-2 LDS reads done before next rep overwrites
  }

  // store partials: aggp[((b*16+sp)*64 + k)*Dp + d]
  float* outb = aggp + (size_t)((b << 4) + sp) * Kn * Dp;
#pragma unroll
  for (int kt = 0; kt < 4; ++kt)
#pragma unroll
    for (int dt = 0; dt < 4; ++dt) {
      const int krow = kt * 16 + (lg << 2);
      const int dcol = wv * 64 + dt * 16 + ll;
      float* op = outb + (size_t)krow * Dp + dcol;
#pragma unroll
      for (int r = 0; r < 4; ++r) op[(size_t)r * Dp] = acc2[kt][dt][r];
    }
}

// ---------------------------------------------------------------------------
// kC1: per (b,k): mass from massp (32 panels); vlad = sum(aggp over 16
// superpanels) - mass*c; intra-normalize over d.
// ---------------------------------------------------------------------------
__device__ __forceinline__ float blockReduceSum(float v, float* sb) {
#pragma unroll
  for (int off = 32; off > 0; off >>= 1) v += __shfl_down(v, off, 64);
  const int lane = threadIdx.x & 63, w = threadIdx.x >> 6;
  if (lane == 0) sb[w] = v;
  __syncthreads();
  if (threadIdx.x == 0) sb[4] = sb[0] + sb[1] + sb[2] + sb[3];
  __syncthreads();
  return sb[4];
}

__global__ __launch_bounds__(256) void kC1(const float* __restrict__ massp,
                                           const float* __restrict__ aggp,
                                           const float* __restrict__ centroids,
                                           float* __restrict__ out,
                                           float* __restrict__ rowsq) {
  __shared__ float sb[5];
  const int tid = threadIdx.x;
  const int b = blockIdx.x >> 6, k = blockIdx.x & 63;
  float s = 0.f;
  if (tid < 32) s = massp[((b << 5) + tid) * Kn + k];
  const float mass = blockReduceSum(s, sb);
  float v[2];
  float sq = 0.f;
#pragma unroll
  for (int u = 0; u < 2; ++u) {
    const int d = tid + (u << 8);
    float val = -mass * centroids[k * Dn + d];
#pragma unroll
    for (int pp = 0; pp < 16; ++pp)
      val += aggp[((size_t)((b << 4) + pp) * Kn + k) * Dp + d];
    v[u] = val;
    sq = fmaf(val, val, sq);
  }
  const float rsq = blockReduceSum(sq, sb);
  const float inv = 1.f / fmaxf(sqrtf(rsq), FEPS);
#pragma unroll
  for (int u = 0; u < 2; ++u)
    out[((size_t)b * Kn + k) * Dn + tid + (u << 8)] = v[u] * inv;
  if (tid == 0) rowsq[b * Kn + k] = rsq * inv * inv;
}

// ---------------------------------------------------------------------------
// kC2: final global L2 norm per batch.
// ---------------------------------------------------------------------------
__global__ __launch_bounds__(256) void kC2(float* __restrict__ out,
                                           const float* __restrict__ rowsq) {
  __shared__ float sg;
  const int b = blockIdx.x, tid = threadIdx.x;
  float v = (tid < 64) ? rowsq[b * Kn + tid] : 0.f;
  if (tid < 64) {
#pragma unroll
    for (int off = 32; off > 0; off >>= 1) v += __shfl_down(v, off, 64);
  }
  if (tid == 0) sg = 1.f / fmaxf(sqrtf(v), FEPS);
  __syncthreads();
  const float inv = sg;
  float* ob = out + (size_t)b * (Kn * Dn);
  for (int t = tid; t < Kn * Dn; t += 256) ob[t] *= inv;
}

// ---------------------------------------------------------------------------
extern "C" void kernel_launch(void* const* d_in, const int* in_sizes, int n_in,
                              void* d_out, int out_size, void* d_ws,
                              size_t ws_size, hipStream_t stream) {
  const float* x = (const float*)d_in[0];
  const float* centroids = (const float*)d_in[1];
  const float* conv_w = (const float*)d_in[2];
  const float* conv_b = (const float*)d_in[3];
  float* out = (float*)d_out;
  float* ws = (float*)d_ws;
  // ws layout (float units):
  //   xp      [0,        34603008)  16 b x 512 d x Npitch(4224) f32
  //   aggp    [34603008, 43122688)  16 b x 16 sp x 64 k x Dp(520) f32
  //   w_hi    [43122688, 43139072)  64x512 bf16 = 16384 floats
  //   w_lo    [43139072, 43155456)
  //   massp   [43155456, 43188224)  16 b x 32 p x 64 k
  //   rowsq   [43188224, 43189248)
  float* xp = ws;
  float* aggp = ws + 34603008;
  unsigned short* w_hi = (unsigned short*)(ws + 43122688);
  unsigned short* w_lo = (unsigned short*)(ws + 43139072);
  float* massp = ws + 43155456;
  float* rowsq = ws + 43188224;

  kX<<<2048, 256, 0, stream>>>(x, xp);
  kW<<<128, 256, 0, stream>>>(conv_w, w_hi, w_lo);
  kF<<<256, 512, 0, stream>>>(xp, w_hi, w_lo, conv_b, aggp, massp);
  kC1<<<1024, 256, 0, stream>>>(massp, aggp, centroids, out, rowsq);
  kC2<<<16, 256, 0, stream>>>(out, rowsq);
}

// Round 15
// 136.401 us; speedup vs baseline: 1.2765x; 1.1852x over previous
//
#include <hip/hip_runtime.h>
#include <cstddef>

constexpr int Bn = 16, Dn = 512, Nn = 4096, Kn = 64;
constexpr int PN = 128;            // panel n-size
constexpr int Dp = 520;            // padded aggp pitch (non-pow2)
constexpr int ASP = 528;           // as_hi pitch per ng (ushorts): word-pitch ≡ 8 mod 32
constexpr float FEPS = 1e-12f;

typedef __bf16 bf16x8 __attribute__((ext_vector_type(8)));
typedef float f32x4 __attribute__((ext_vector_type(4)));

__device__ __forceinline__ unsigned short bf_bits(__bf16 h) {
  union { __bf16 b; unsigned short u; } c;
  c.b = h;
  return c.u;
}

// ---------------------------------------------------------------------------
// kW: split conv_w[K][D] (row-major, d-contiguous) into bf16 hi/lo arrays.
// ---------------------------------------------------------------------------
__global__ __launch_bounds__(256) void kW(const float* __restrict__ w,
                                          unsigned short* __restrict__ w_hi,
                                          unsigned short* __restrict__ w_lo) {
  const int idx = blockIdx.x * 256 + threadIdx.x;  // 32768 total
  const float v = w[idx];
  const __bf16 h = (__bf16)v;          // RNE
  const float r = v - (float)h;
  const __bf16 l = (__bf16)r;
  w_hi[idx] = bf_bits(h);
  w_lo[idx] = bf_bits(l);
}

// ---------------------------------------------------------------------------
// kF v7 = R12's validated kernel with DEPTH-4 register prefetch (the R13
// concept minus its spill: acc2 is now phase-2-local, so phase-1 live
// registers fit). Math bit-identical to R12. Per-rep aggp partials (32/b).
// Block = (b, superpanel sp of 256 n), 512 thr = 8 waves, grid 256.
// ---------------------------------------------------------------------------
__global__ __launch_bounds__(512, 2) void kF(const float* __restrict__ x,
                                             const unsigned short* __restrict__ w_hi,
                                             const unsigned short* __restrict__ w_lo,
                                             const float* __restrict__ conv_b,
                                             float* __restrict__ aggp,
                                             float* __restrict__ massp) {
  __shared__ float xs[PN * 33];             // staging / as_hi reuse
  __shared__ unsigned short xhi[Dn * PN];   // persistent bf16-hi panel
  __shared__ float msum[8][64];
  const int tid = threadIdx.x;
  const int l = tid & 63;
  const int wv = tid >> 6;   // 0..7
  const int ll = l & 15;
  const int lg = l >> 4;
  const int b = blockIdx.x >> 4;
  const int sp = blockIdx.x & 15;
  const int srow = tid >> 4;        // 0..31 (staging row within 32-d chunk)
  const int sc0 = (tid & 15) << 3;  // staging col (8 n per thread)
  const int ncol = (wv << 4) + ll;  // phase-1 n within panel

  for (int rep = 0; rep < 2; ++rep) {
    const int p = (sp << 1) + rep;
    const int n0 = p << 7;
    const float* xbp = x + (size_t)b * Dn * Nn + n0;

    // =================== Phase 1: logits (validated math) ===================
    f32x4 acc[4];
#pragma unroll
    for (int kt = 0; kt < 4; ++kt) acc[kt] = (f32x4){0.f, 0.f, 0.f, 0.f};
    float ss = 0.f;

    // 4-deep prefetch: issue chunks 0..3 (8 loads, 128 B/thread in flight)
    float4 pf[4][2];
#pragma unroll
    for (int s = 0; s < 4; ++s) {
      const float* src = xbp + (size_t)(s * 32 + srow) * Nn + sc0;
      pf[s][0] = *(const float4*)(src);
      pf[s][1] = *(const float4*)(src + 4);
    }

#pragma unroll 4
    for (int it = 0; it < 16; ++it) {
      const int s = it & 3;          // static within unroll-4 group
      const int dc = it * 32;
      // ---- store stage s (fp32 transposed + bf16-hi panel) ----
      {
        const float pv[8] = {pf[s][0].x, pf[s][0].y, pf[s][0].z, pf[s][0].w,
                             pf[s][1].x, pf[s][1].y, pf[s][1].z, pf[s][1].w};
#pragma unroll
        for (int j = 0; j < 8; ++j) xs[(sc0 + j) * 33 + srow] = pv[j];
        unsigned short hb[8];
#pragma unroll
        for (int j = 0; j < 8; ++j) hb[j] = bf_bits((__bf16)pv[j]);
        const unsigned byteoff =
            (unsigned)(((dc + srow) * PN + sc0) * 2) ^ ((unsigned)(srow & 7) << 4);
        uint4 hv;
        hv.x = (unsigned)hb[0] | ((unsigned)hb[1] << 16);
        hv.y = (unsigned)hb[2] | ((unsigned)hb[3] << 16);
        hv.z = (unsigned)hb[4] | ((unsigned)hb[5] << 16);
        hv.w = (unsigned)hb[6] | ((unsigned)hb[7] << 16);
        *(uint4*)((char*)xhi + byteoff) = hv;
      }
      // ---- refill stage s with chunk it+4 ----
      if (it < 12) {
        const float* src = xbp + (size_t)(dc + 128 + srow) * Nn + sc0;
        pf[s][0] = *(const float4*)(src);
        pf[s][1] = *(const float4*)(src + 4);
      }
      asm volatile("s_waitcnt lgkmcnt(0)\ns_barrier" ::: "memory");

      // ---- consume chunk dc ----
      float xv[8];
#pragma unroll
      for (int j = 0; j < 8; ++j) xv[j] = xs[ncol * 33 + lg * 8 + j];
      bf16x8 bh, bl;
#pragma unroll
      for (int j = 0; j < 8; ++j) {
        ss = fmaf(xv[j], xv[j], ss);
        const __bf16 h = (__bf16)xv[j];
        bh[j] = h;
        bl[j] = (__bf16)(xv[j] - (float)h);
      }
#pragma unroll
      for (int kt = 0; kt < 4; ++kt) {
        const size_t woff = (size_t)(kt * 16 + ll) * Dn + dc + lg * 8;
        bf16x8 ah = *(const bf16x8*)(w_hi + woff);
        bf16x8 al = *(const bf16x8*)(w_lo + woff);
        acc[kt] = __builtin_amdgcn_mfma_f32_16x16x32_bf16(ah, bh, acc[kt], 0, 0, 0);
        acc[kt] = __builtin_amdgcn_mfma_f32_16x16x32_bf16(ah, bl, acc[kt], 0, 0, 0);
        acc[kt] = __builtin_amdgcn_mfma_f32_16x16x32_bf16(al, bh, acc[kt], 0, 0, 0);
      }
      asm volatile("s_waitcnt lgkmcnt(0)\ns_barrier" ::: "memory");
    }

    // ---- softmax (in-register, validated) ----
    ss += __shfl_xor(ss, 16);
    ss += __shfl_xor(ss, 32);
    const float iv = 1.f / fmaxf(sqrtf(ss), FEPS);
    float lgt[16];
#pragma unroll
    for (int kt = 0; kt < 4; ++kt)
#pragma unroll
      for (int r = 0; r < 4; ++r)
        lgt[kt * 4 + r] = fmaf(acc[kt][r], iv, conv_b[kt * 16 + lg * 4 + r]);
    float pmax = lgt[0];
#pragma unroll
    for (int i = 1; i < 16; ++i) pmax = fmaxf(pmax, lgt[i]);
    pmax = fmaxf(pmax, __shfl_xor(pmax, 16));
    pmax = fmaxf(pmax, __shfl_xor(pmax, 32));
    float ex[16];
    float psum = 0.f;
#pragma unroll
    for (int i = 0; i < 16; ++i) {
      ex[i] = expf(lgt[i] - pmax);
      psum += ex[i];
    }
    psum += __shfl_xor(psum, 16);
    psum += __shfl_xor(psum, 32);
    const float isum = 1.f / psum;

    __syncthreads();  // xs reads done; reuse as as_hi

    unsigned short* as_hi = (unsigned short*)xs;  // [ng16][ASP] bf16
    const int ngb = (wv << 1) + (ll >> 3);
    const int jj = ll & 7;
#pragma unroll
    for (int i = 0; i < 16; ++i) {
      const int k = (i >> 2) * 16 + lg * 4 + (i & 3);
      const float a = ex[i] * isum;
      as_hi[ngb * ASP + k * 8 + jj] = bf_bits((__bf16)(a * iv));
      float m = a;
      m += __shfl_xor(m, 1);
      m += __shfl_xor(m, 2);
      m += __shfl_xor(m, 4);
      m += __shfl_xor(m, 8);
      if (ll == 0) msum[wv][k] = m;
    }
    __syncthreads();
    if (tid < 64) {
      float s = 0.f;
#pragma unroll
      for (int ww = 0; ww < 8; ++ww) s += msum[ww][tid];
      massp[((b << 5) + p) * Kn + tid] = s;
    }

    // =================== Phase 2: agg from LDS (acc2 local) ===================
    f32x4 acc2[4][4];
#pragma unroll
    for (int kt = 0; kt < 4; ++kt)
#pragma unroll
      for (int dt = 0; dt < 4; ++dt) acc2[kt][dt] = (f32x4){0.f, 0.f, 0.f, 0.f};

#pragma unroll
    for (int nc = 0; nc < PN; nc += 32) {
      const int ng = (nc >> 3) + lg;
      bf16x8 af[4];
#pragma unroll
      for (int kt = 0; kt < 4; ++kt)
        af[kt] = *(const bf16x8*)(as_hi + ng * ASP + (kt * 16 + ll) * 8);
#pragma unroll
      for (int dt = 0; dt < 4; ++dt) {
        const int d = wv * 64 + dt * 16 + ll;
        const unsigned byteoff =
            (unsigned)((d * PN + nc + lg * 8) * 2) ^ ((unsigned)(d & 7) << 4);
        bf16x8 bx = *(const bf16x8*)((const char*)xhi + byteoff);
#pragma unroll
        for (int kt = 0; kt < 4; ++kt)
          acc2[kt][dt] = __builtin_amdgcn_mfma_f32_16x16x32_bf16(
              af[kt], bx, acc2[kt][dt], 0, 0, 0);
      }
    }

    // store this panel's partials: aggp[((b*32+p)*64 + k)*Dp + d]
    float* outb = aggp + (size_t)((b << 5) + p) * Kn * Dp;
#pragma unroll
    for (int kt = 0; kt < 4; ++kt)
#pragma unroll
      for (int dt = 0; dt < 4; ++dt) {
        const int krow = kt * 16 + (lg << 2);
        const int dcol = wv * 64 + dt * 16 + ll;
        float* op = outb + (size_t)krow * Dp + dcol;
#pragma unroll
        for (int r = 0; r < 4; ++r) op[(size_t)r * Dp] = acc2[kt][dt][r];
      }
    __syncthreads();  // phase-2 LDS reads done before next rep overwrites
  }
}

// ---------------------------------------------------------------------------
// kC1: per (b,k): mass from massp (32 panels); vlad = sum(aggp over 32
// panels) - mass*c; intra-normalize over d.
// ---------------------------------------------------------------------------
__device__ __forceinline__ float blockReduceSum(float v, float* sb) {
#pragma unroll
  for (int off = 32; off > 0; off >>= 1) v += __shfl_down(v, off, 64);
  const int lane = threadIdx.x & 63, w = threadIdx.x >> 6;
  if (lane == 0) sb[w] = v;
  __syncthreads();
  if (threadIdx.x == 0) sb[4] = sb[0] + sb[1] + sb[2] + sb[3];
  __syncthreads();
  return sb[4];
}

__global__ __launch_bounds__(256) void kC1(const float* __restrict__ massp,
                                           const float* __restrict__ aggp,
                                           const float* __restrict__ centroids,
                                           float* __restrict__ out,
                                           float* __restrict__ rowsq) {
  __shared__ float sb[5];
  const int tid = threadIdx.x;
  const int b = blockIdx.x >> 6, k = blockIdx.x & 63;
  float s = 0.f;
  if (tid < 32) s = massp[((b << 5) + tid) * Kn + k];
  const float mass = blockReduceSum(s, sb);
  float v[2];
  float sq = 0.f;
#pragma unroll
  for (int u = 0; u < 2; ++u) {
    const int d = tid + (u << 8);
    float val = -mass * centroids[k * Dn + d];
#pragma unroll 8
    for (int pp = 0; pp < 32; ++pp)
      val += aggp[((size_t)((b << 5) + pp) * Kn + k) * Dp + d];
    v[u] = val;
    sq = fmaf(val, val, sq);
  }
  const float rsq = blockReduceSum(sq, sb);
  const float inv = 1.f / fmaxf(sqrtf(rsq), FEPS);
#pragma unroll
  for (int u = 0; u < 2; ++u)
    out[((size_t)b * Kn + k) * Dn + tid + (u << 8)] = v[u] * inv;
  if (tid == 0) rowsq[b * Kn + k] = rsq * inv * inv;
}

// ---------------------------------------------------------------------------
// kC2: final global L2 norm per batch.
// ---------------------------------------------------------------------------
__global__ __launch_bounds__(256) void kC2(float* __restrict__ out,
                                           const float* __restrict__ rowsq) {
  __shared__ float sg;
  const int b = blockIdx.x, tid = threadIdx.x;
  float v = (tid < 64) ? rowsq[b * Kn + tid] : 0.f;
  if (tid < 64) {
#pragma unroll
    for (int off = 32; off > 0; off >>= 1) v += __shfl_down(v, off, 64);
  }
  if (tid == 0) sg = 1.f / fmaxf(sqrtf(v), FEPS);
  __syncthreads();
  const float inv = sg;
  float* ob = out + (size_t)b * (Kn * Dn);
  for (int t = tid; t < Kn * Dn; t += 256) ob[t] *= inv;
}

// ---------------------------------------------------------------------------
extern "C" void kernel_launch(void* const* d_in, const int* in_sizes, int n_in,
                              void* d_out, int out_size, void* d_ws,
                              size_t ws_size, hipStream_t stream) {
  const float* x = (const float*)d_in[0];
  const float* centroids = (const float*)d_in[1];
  const float* conv_w = (const float*)d_in[2];
  const float* conv_b = (const float*)d_in[3];
  float* out = (float*)d_out;
  float* ws = (float*)d_ws;
  // ws layout (float units):
  //   aggp    [0,        17039360)  16 b x 32 p x 64 k x Dp(520) f32
  //   w_hi    [17039360, 17055744)  64x512 bf16 = 16384 floats
  //   w_lo    [17055744, 17072128)
  //   massp   [17072128, 17104896)  16 b x 32 p x 64 k
  //   rowsq   [17104896, 17105920)
  float* aggp = ws;
  unsigned short* w_hi = (unsigned short*)(ws + 17039360);
  unsigned short* w_lo = (unsigned short*)(ws + 17055744);
  float* massp = ws + 17072128;
  float* rowsq = ws + 17104896;

  kW<<<128, 256, 0, stream>>>(conv_w, w_hi, w_lo);
  kF<<<256, 512, 0, stream>>>(x, w_hi, w_lo, conv_b, aggp, massp);
  kC1<<<1024, 256, 0, stream>>>(massp, aggp, centroids, out, rowsq);
  kC2<<<16, 256, 0, stream>>>(out, rowsq);
}